// Round 1
// baseline (19112.526 us; speedup 1.0000x reference)
//
#include <hip/hip_runtime.h>

typedef unsigned short u16;
typedef short bf16x8 __attribute__((ext_vector_type(8)));
typedef float f32x4 __attribute__((ext_vector_type(4)));

#define SS 2048   // sequence length
#define BB 64     // batch
#define HH 512    // hidden
#define GG 2048   // 4*H gates

// ws layout (bytes)
#define WB_ELEMS (2048 * 1024)            // packed bf16 weight frags
#define OFF_BIAS ((size_t)WB_ELEMS * 2)   // 4,194,304
#define OFF_C    (OFF_BIAS + 2048 * 4)    // 4,202,496  (c state, fp32, 64*512)
#define OFF_H0   (OFF_C + 32768 * 4)      // 4,333,568  (h slot0, bf16)
#define OFF_H1   (OFF_H0 + 32768 * 2)     // 4,399,104  (h slot1, bf16)
#define WS_NEED  (OFF_H1 + 32768 * 2)     // 4,464,640 total

__device__ __forceinline__ u16 f2bf(float f) {
    unsigned int u = __builtin_bit_cast(unsigned int, f);
    u += 0x7FFFu + ((u >> 16) & 1u);   // round-to-nearest-even
    return (u16)(u >> 16);
}

// Permuted gate index: p = w*32 + q*8 + (h&7), w = h>>3, q = gate (0=i,1=f,2=g,3=o).
// Wave w owns columns [32w, 32w+32) = hidden units [8w, 8w+8) x 4 gates.
// decode: q = (p>>3)&3 ; h = ((p>>5)<<3) | (p&7) ; original row = q*512 + h.

// Packed B-frag layout: WB[gt][kc][lane][j], gt=0..127 (16-col n-tile), kc=0..31 (K-chunk of 32),
// value = Wcat[p = gt*16 + (lane&15)][k = kc*32 + (lane>>4)*8 + j],
// Wcat[p][k] = k<512 ? Wih[row(p)][k] : Whh[row(p)][k-512]. 16B contiguous per lane.
__global__ __launch_bounds__(256) void lstm_prep(
    const float* __restrict__ Wih, const float* __restrict__ Whh,
    const float* __restrict__ bih, const float* __restrict__ bhh,
    const float* __restrict__ h_prev, const float* __restrict__ c_prev,
    u16* __restrict__ WB, float* __restrict__ bias_p,
    float* __restrict__ c_ws, u16* __restrict__ h0)
{
    int idx = blockIdx.x * 256 + threadIdx.x;
    if (idx < WB_ELEMS) {
        int j    = idx & 7;
        int lane = (idx >> 3) & 63;
        int kc   = (idx >> 9) & 31;
        int gt   = idx >> 14;
        int p = gt * 16 + (lane & 15);
        int k = kc * 32 + (lane >> 4) * 8 + j;
        int q = (p >> 3) & 3;
        int h = ((p >> 5) << 3) | (p & 7);
        int row = q * 512 + h;
        float v = (k < 512) ? Wih[row * 512 + k] : Whh[row * 512 + (k - 512)];
        WB[idx] = f2bf(v);
    } else if (idx < WB_ELEMS + 2048) {
        int p = idx - WB_ELEMS;
        int q = (p >> 3) & 3;
        int h = ((p >> 5) << 3) | (p & 7);
        int row = q * 512 + h;
        bias_p[p] = bih[row] + bhh[row];
    } else if (idx < WB_ELEMS + 2048 + 32768) {
        int i = idx - (WB_ELEMS + 2048);
        c_ws[i] = c_prev[i];
    } else if (idx < WB_ELEMS + 2048 + 65536) {
        int i = idx - (WB_ELEMS + 2048 + 32768);
        h0[i] = f2bf(h_prev[i]);
    }
}

// One LSTM timestep. Grid 256 blocks x 64 threads (1 wave each).
// wave wid: b-tile = (wid&3)*16, hid-group w = wid>>2 (hids 8w..8w+8, 2 n-tiles of 16 cols).
// K = 1024: chunks 0..15 from x_t (fp32->bf16 in-reg), 16..31 from h_{t-1} (bf16 slot).
__global__ __launch_bounds__(64) void lstm_step(
    const float* __restrict__ x_all, const u16* __restrict__ WB,
    const float* __restrict__ bias_p, float* __restrict__ c_ws,
    const u16* __restrict__ h_in, u16* __restrict__ h_out,
    float* __restrict__ out, float* __restrict__ hf, float* __restrict__ cf,
    int t)
{
    int lane = threadIdx.x;
    int wid  = blockIdx.x;
    int b0   = (wid & 3) * 16;
    int w    = wid >> 2;
    int col  = lane & 15;
    int quad = lane >> 4;

    f32x4 acc0 = {0.f, 0.f, 0.f, 0.f};
    f32x4 acc1 = {0.f, 0.f, 0.f, 0.f};

    int ba = b0 + col;  // A-frag row m = lane&15
    const float* xrow = x_all + ((size_t)t * BB + ba) * 512 + quad * 8;
    const u16*  hrow  = h_in + ba * 512 + quad * 8;
    const u16*  wb0   = WB + (size_t)(w * 2) * 32 * 64 * 8 + lane * 8;
    const u16*  wb1   = WB + (size_t)(w * 2 + 1) * 32 * 64 * 8 + lane * 8;

#pragma unroll
    for (int kc = 0; kc < 16; ++kc) {
        const float* px = xrow + kc * 32;
        float4 fa = *(const float4*)(px);
        float4 fb = *(const float4*)(px + 4);
        bf16x8 a;
        a[0] = (short)f2bf(fa.x); a[1] = (short)f2bf(fa.y);
        a[2] = (short)f2bf(fa.z); a[3] = (short)f2bf(fa.w);
        a[4] = (short)f2bf(fb.x); a[5] = (short)f2bf(fb.y);
        a[6] = (short)f2bf(fb.z); a[7] = (short)f2bf(fb.w);
        bf16x8 bf0 = *(const bf16x8*)(wb0 + (size_t)kc * 64 * 8);
        bf16x8 bf1 = *(const bf16x8*)(wb1 + (size_t)kc * 64 * 8);
        acc0 = __builtin_amdgcn_mfma_f32_16x16x32_bf16(a, bf0, acc0, 0, 0, 0);
        acc1 = __builtin_amdgcn_mfma_f32_16x16x32_bf16(a, bf1, acc1, 0, 0, 0);
    }
#pragma unroll
    for (int kc = 16; kc < 32; ++kc) {
        bf16x8 a = *(const bf16x8*)(hrow + (kc - 16) * 32);
        bf16x8 bf0 = *(const bf16x8*)(wb0 + (size_t)kc * 64 * 8);
        bf16x8 bf1 = *(const bf16x8*)(wb1 + (size_t)kc * 64 * 8);
        acc0 = __builtin_amdgcn_mfma_f32_16x16x32_bf16(a, bf0, acc0, 0, 0, 0);
        acc1 = __builtin_amdgcn_mfma_f32_16x16x32_bf16(a, bf1, acc1, 0, 0, 0);
    }

    // Epilogue: lane (col<8) holds gates (i, g) for hid; partner lane^8 holds (f, o).
    int hid = (w << 3) | (col & 7);
    bool lo = (col & 8) == 0;
    float blo = bias_p[w * 32 + col];
    float bhi = bias_p[w * 32 + 16 + col];
    bool last = (t == SS - 1);

#pragma unroll
    for (int r = 0; r < 4; ++r) {
        int bb = b0 + quad * 4 + r;          // C/D row = quad*4 + reg
        float v0 = acc0[r] + blo;
        float v1 = acc1[r] + bhi;
        float o0 = __shfl_xor(v0, 8);
        float o1 = __shfl_xor(v1, 8);
        if (lo) {
            float gi = v0, gf = o0, gg = v1, go = o1;
            float i_ = 1.f / (1.f + __expf(-gi));
            float f_ = 1.f / (1.f + __expf(-gf));
            float g_ = 2.f / (1.f + __expf(-2.f * gg)) - 1.f;
            float o_ = 1.f / (1.f + __expf(-go));
            int idx = bb * 512 + hid;
            float c_old = c_ws[idx];
            float c_new = f_ * c_old + i_ * g_;
            float tc = 2.f / (1.f + __expf(-2.f * c_new)) - 1.f;
            float h_new = o_ * tc;
            c_ws[idx] = c_new;
            out[(size_t)t * (BB * HH) + idx] = h_new;
            h_out[idx] = f2bf(h_new);
            if (last) { hf[idx] = h_new; cf[idx] = c_new; }
        }
    }
}

extern "C" void kernel_launch(void* const* d_in, const int* in_sizes, int n_in,
                              void* d_out, int out_size, void* d_ws, size_t ws_size,
                              hipStream_t stream) {
    const float* x      = (const float*)d_in[0];
    const float* h_prev = (const float*)d_in[1];
    const float* c_prev = (const float*)d_in[2];
    const float* Wih    = (const float*)d_in[3];
    const float* Whh    = (const float*)d_in[4];
    const float* bih    = (const float*)d_in[5];
    const float* bhh    = (const float*)d_in[6];
    float* out = (float*)d_out;

    if (ws_size < WS_NEED) return;  // cannot run without scratch

    char* ws = (char*)d_ws;
    u16*   WB     = (u16*)ws;
    float* bias_p = (float*)(ws + OFF_BIAS);
    float* c_ws   = (float*)(ws + OFF_C);
    u16*   h0     = (u16*)(ws + OFF_H0);
    u16*   h1     = (u16*)(ws + OFF_H1);

    int prep_threads = WB_ELEMS + 2048 + 65536;
    int prep_blocks = (prep_threads + 255) / 256;
    hipLaunchKernelGGL(lstm_prep, dim3(prep_blocks), dim3(256), 0, stream,
                       Wih, Whh, bih, bhh, h_prev, c_prev, WB, bias_p, c_ws, h0);

    float* hf = out + (size_t)SS * BB * HH;
    float* cf = hf + BB * HH;
    for (int t = 0; t < SS; ++t) {
        const u16* hin = (t & 1) ? h1 : h0;
        u16* hout      = (t & 1) ? h0 : h1;
        hipLaunchKernelGGL(lstm_step, dim3(256), dim3(64), 0, stream,
                           x, WB, bias_p, c_ws, hin, hout, out, hf, cf, t);
    }
}